// Round 3
// baseline (7879.832 us; speedup 1.0000x reference)
//
#include <hip/hip_runtime.h>
#include <hip/hip_bf16.h>

using bf16 = __hip_bfloat16;
typedef __attribute__((ext_vector_type(8))) short bf16x8;
typedef __attribute__((ext_vector_type(4))) float f32x4;

__device__ __forceinline__ void gload16(const void* g, void* l) {
  __builtin_amdgcn_global_load_lds((const __attribute__((address_space(1))) void*)g,
                                   (__attribute__((address_space(3))) void*)l, 16, 0, 0);
}

__device__ __forceinline__ float sigm(float x) { return 1.0f / (1.0f + __expf(-x)); }
// overflow-safe fast tanh
__device__ __forceinline__ float ftanh(float x) {
  float e = __expf(2.0f * fabsf(x));
  return copysignf(1.0f - 2.0f / (e + 1.0f), x);
}

#define MFMA16(a, b, c) __builtin_amdgcn_mfma_f32_16x16x32_bf16(a, b, c, 0, 0, 0)

#define RD 16  // h1 ring depth == segment length (t==0 never reads ring)

// ---------------------------------------------------------------------------
// Persistent recurrent kernel: 256 blocks x 512 thr, one block per CU.
// Each block owns output tile (nt,mt): 64 gate-cols x 64 batch-rows, for all
// 256 steps x 2 layers. Global sync via monotonic-epoch barrier.
// Coherence: writes flushed by release-fence(agent) (buffer_wbl2); readers
// always read FRESH addresses (h1 ring depth 16, hist append-only) so no
// L2 invalidate is needed -> weight tiles stay L2-resident.
// ---------------------------------------------------------------------------
__global__ __launch_bounds__(512) void rnn_persist(
    const bf16* __restrict__ wHH1, const bf16* __restrict__ wFOLD,
    const bf16* __restrict__ wIH2, const bf16* __restrict__ wHH2,
    const float* __restrict__ PE1, const float* __restrict__ b2r,
    const float* __restrict__ bfr,
    const bf16* __restrict__ h1i, const bf16* __restrict__ h2i,
    const float* __restrict__ c1i, const float* __restrict__ c2i,
    bf16* __restrict__ h1ring, bf16* __restrict__ hist,
    unsigned* __restrict__ bar)
{
  const size_t S = 256ull * 1024;
  const int tid = threadIdx.x;
  const int wv = tid >> 6, ln = tid & 63, grp = wv >> 2, wg = wv & 3;
  // XCD-aware mapping: the 4 mt-blocks sharing weight rows land on one XCD
  const int xcd = blockIdx.x & 7, slot = blockIdx.x >> 3;
  const int nt = (xcd << 3) | (slot & 7), mt = slot >> 3;
  const int m0 = mt << 6, n0 = nt << 6;
  const int wm = (wg >> 1) << 5, wn = (wg & 1) << 5;

  __shared__ __attribute__((aligned(128))) char smem[65536];
  char* gbase = smem + (grp << 15);

  // epilogue identity: thread -> (batch rows emr, emr+32) x hidden col eh
  const int eh = tid & 15, emr = tid >> 4;
  const int ehg = (nt << 4) + eh;

  f32x4 acc00, acc01, acc10, acc11;
  float c1r[2], c2r[2];
  unsigned ep = 0;

  auto stageA = [&](int kb, const bf16* asrc) {
    char* As = gbase + ((kb & 1) << 14);
    const int k0b = kb << 7;
#pragma unroll
    for (int i = 0; i < 2; ++i) {
      int rr = ((i << 2) + wg) * 8 + (ln >> 3);
      int sc = (ln & 7) ^ (rr & 7);
      gload16((const char*)asrc + ((size_t)(m0 + rr) << 11) + k0b + (sc << 4),
              As + (((i << 2) + wg) << 10));
    }
  };
  auto stageB = [&](int kb, const bf16* wsrc) {
    char* Bs = gbase + ((kb & 1) << 14) + 8192;
    const int k0b = kb << 7;
#pragma unroll
    for (int i = 0; i < 2; ++i) {
      int rr = ((i << 2) + wg) * 8 + (ln >> 3);
      int sc = (ln & 7) ^ (rr & 7);
      gload16((const char*)wsrc + ((size_t)(n0 + rr) << 11) + k0b + (sc << 4),
              Bs + (((i << 2) + wg) << 10));
    }
  };

  // K-loop; assumes A(0)+B(0) already staged into buf0
  auto gemm = [&](const bf16* asrc, const bf16* wsrc) {
    acc00 = f32x4{0.f, 0.f, 0.f, 0.f}; acc01 = acc00; acc10 = acc00; acc11 = acc00;
    for (int kb = 0; kb < 16; ++kb) {
      asm volatile("s_waitcnt vmcnt(0)" ::: "memory");
      __builtin_amdgcn_s_barrier();
      asm volatile("" ::: "memory");
      if (kb + 1 < 16) { stageA(kb + 1, asrc); stageB(kb + 1, wsrc); }
      const char* As = gbase + ((kb & 1) << 14);
      const char* Bs = As + 8192;
      __builtin_amdgcn_s_setprio(1);
#pragma unroll
      for (int ks = 0; ks < 2; ++ks) {
        const int kc = (ks << 2) + (ln >> 4);
        auto ld = [&](const char* base, int row) -> bf16x8 {
          return *(const bf16x8*)(base + row * 128 + ((kc ^ (row & 7)) << 4));
        };
        bf16x8 A0 = ld(As, wm + (ln & 15));
        bf16x8 A1 = ld(As, wm + 16 + (ln & 15));
        bf16x8 B0 = ld(Bs, wn + (ln & 15));
        bf16x8 B1 = ld(Bs, wn + 16 + (ln & 15));
        acc00 = MFMA16(A0, B0, acc00);
        acc01 = MFMA16(A0, B1, acc01);
        acc10 = MFMA16(A1, B0, acc10);
        acc11 = MFMA16(A1, B1, acc11);
      }
      __builtin_amdgcn_s_setprio(0);
    }
  };

  auto epilogue = [&](bool dual, const float* pe, const float* bias, const float* bsub,
                      bool loadc, const float* ci, float* creg, bf16* hout) {
    __syncthreads();
    float* gs = (float*)smem;  // [2][64][68]
#pragma unroll
    for (int mi = 0; mi < 2; ++mi)
#pragma unroll
      for (int ni = 0; ni < 2; ++ni) {
        f32x4 a = (mi == 0) ? (ni == 0 ? acc00 : acc01) : (ni == 0 ? acc10 : acc11);
#pragma unroll
        for (int r = 0; r < 4; ++r) {
          int row = wm + mi * 16 + ((ln >> 4) << 2) + r;
          int col = wn + ni * 16 + (ln & 15);
          gs[grp * 4352 + row * 68 + col] = a[r];
        }
      }
    __syncthreads();
#pragma unroll
    for (int half = 0; half < 2; ++half) {
      int m = emr + (half << 5);
      int gm = m0 + m;
      float4 v = *(const float4*)(gs + m * 68 + (eh << 2));
      float g0 = v.x, g1 = v.y, g2 = v.z, g3 = v.w;
      if (dual) {
        float4 u = *(const float4*)(gs + 4352 + m * 68 + (eh << 2));
        g0 += u.x; g1 += u.y; g2 += u.z; g3 += u.w;
      }
      int nb = n0 + (eh << 2);
      if (pe) {
        float4 pv = *(const float4*)(pe + (size_t)gm * 4096 + nb);
        g0 += pv.x; g1 += pv.y; g2 += pv.z; g3 += pv.w;
      }
      if (bias) {
        float4 bv = *(const float4*)(bias + nb);
        g0 += bv.x; g1 += bv.y; g2 += bv.z; g3 += bv.w;
      }
      if (bsub) {
        float4 sv = *(const float4*)(bsub + nb);
        g0 -= sv.x; g1 -= sv.y; g2 -= sv.z; g3 -= sv.w;
      }
      float ig = sigm(g0), fg = sigm(g1), gg = ftanh(g2), og = sigm(g3);
      size_t idx = (size_t)gm * 1024 + ehg;
      float cc = loadc ? ci[idx] : creg[half];
      float cn = fg * cc + ig * gg;
      creg[half] = cn;
      hout[idx] = __float2bfloat16(og * ftanh(cn));
    }
    __syncthreads();  // gs reads done before buf0 prefetch overwrites
  };

  auto gbar = [&]() {
    __syncthreads();  // drains each wave's vmcnt (incl. h stores) before barrier
    if (tid == 0) {
      __builtin_amdgcn_fence(__ATOMIC_RELEASE, "agent");  // wbl2: push stores to LLC
      unsigned arr = __hip_atomic_fetch_add(bar, 1u, __ATOMIC_RELAXED,
                                            __HIP_MEMORY_SCOPE_AGENT);
      if (arr == ep * 256u + 255u) {
        __hip_atomic_store(bar + 32, ep + 1u, __ATOMIC_RELAXED,
                           __HIP_MEMORY_SCOPE_AGENT);
      } else {
        while (__hip_atomic_load(bar + 32, __ATOMIC_RELAXED,
                                 __HIP_MEMORY_SCOPE_AGENT) <= ep)
          __builtin_amdgcn_s_sleep(2);
      }
    }
    __syncthreads();
    asm volatile("" ::: "memory");
    ep++;
  };

  // ---- prologue: stage layer1(gt=0) tile 0 (both groups read h1i: dup OK) ----
  stageB(0, grp ? wFOLD : wHH1);
  stageA(0, h1i);

  for (int gt = 0; gt < 256; ++gt) {
    const int s = gt >> 4, t = gt & 15;
    // ---- layer 1: g = PE1[s] + h1@wHH1' + h2prev@wFOLD' ----
    const bf16* A1 = (t == 0) ? h1i + (size_t)s * S
                              : h1ring + (size_t)((gt - 1) & (RD - 1)) * S;
    const bf16* A2 = (gt == 0) ? A1 : hist + (size_t)(gt - 1) * S;
    const bf16* sa = grp ? A2 : A1;
    gemm(sa, grp ? wFOLD : wHH1);
    epilogue(gt != 0, PE1 + (size_t)s * 1048576, nullptr, (gt == 0) ? bfr : nullptr,
             t == 0, c1i + (size_t)s * S, c1r,
             h1ring + (size_t)(gt & (RD - 1)) * S);
    // prefetch layer2 tile0: B both groups; A only grp1 (old data, ready)
    const bf16* l2a2 = (t == 0) ? h2i + (size_t)s * S : hist + (size_t)(gt - 1) * S;
    stageB(0, grp ? wHH2 : wIH2);
    if (grp == 1) stageA(0, l2a2);
    gbar();
    // ---- layer 2: g = h1new@wIH2' + h2@wHH2' + b2 ----
    const bf16* l2a1 = h1ring + (size_t)(gt & (RD - 1)) * S;
    if (grp == 0) stageA(0, l2a1);
    gemm(grp ? l2a2 : l2a1, grp ? wHH2 : wIH2);
    epilogue(true, nullptr, b2r, nullptr, t == 0, c2i + (size_t)s * S, c2r,
             hist + (size_t)gt * S);
    // prefetch next layer1 tile0: B both groups; A only grp0 (h1 just written)
    int gn = (gt + 1 < 256) ? gt + 1 : gt;
    int s2 = gn >> 4, t2 = gn & 15;
    const bf16* n1a = (t2 == 0) ? h1i + (size_t)s2 * S
                                : h1ring + (size_t)(gt & (RD - 1)) * S;
    stageB(0, grp ? wFOLD : wHH1);
    if (grp == 0) stageA(0, n1a);
    gbar();
    if (grp == 1) stageA(0, hist + (size_t)gt * S);  // next layer1 A2 (now ready)
  }
}

// ---------------------------------------------------------------------------
// Launch-per-step fallback kernel (round-2 proven path, used if ws too small)
// ---------------------------------------------------------------------------
__global__ __launch_bounds__(512) void rnn_step(
    const bf16* __restrict__ a1, const bf16* __restrict__ a2,
    const bf16* __restrict__ w1, const bf16* __restrict__ w2,
    const float* __restrict__ pe, const float* __restrict__ bias,
    const float* __restrict__ bsub,
    const float* __restrict__ c_in, float* __restrict__ c_out,
    bf16* __restrict__ h_out)
{
  __shared__ __attribute__((aligned(128))) char smem[65536];
  const int tid = threadIdx.x;
  const int wv = tid >> 6, ln = tid & 63;
  const int grp = wv >> 2, wg = wv & 3;
  const int nt = blockIdx.x, mt = blockIdx.y;
  const int m0 = mt << 6, n0 = nt << 6;
  const int wm = (wg >> 1) << 5, wn = (wg & 1) << 5;
  const bool use2 = (a2 != nullptr);

  const bf16* asrc = (grp == 0) ? a1 : (use2 ? a2 : a1);
  const bf16* wsrc = (grp == 0) ? w1 : (use2 ? w2 : w1);
  char* gbase = smem + (grp << 15);

  auto stage = [&](int kb) {
    char* As = gbase + ((kb & 1) << 14);
    char* Bs = As + 8192;
    const int k0b = kb << 7;
#pragma unroll
    for (int i = 0; i < 2; ++i) {
      int rr = ((i << 2) + wg) * 8 + (ln >> 3);
      int sc = (ln & 7) ^ (rr & 7);
      gload16((const char*)asrc + ((size_t)(m0 + rr) << 11) + k0b + (sc << 4),
              As + (((i << 2) + wg) << 10));
      gload16((const char*)wsrc + ((size_t)(n0 + rr) << 11) + k0b + (sc << 4),
              Bs + (((i << 2) + wg) << 10));
    }
  };

  f32x4 acc00{}, acc01{}, acc10{}, acc11{};
  stage(0);
  for (int kb = 0; kb < 16; ++kb) {
    asm volatile("s_waitcnt vmcnt(0)" ::: "memory");
    __builtin_amdgcn_s_barrier();
    asm volatile("" ::: "memory");
    if (kb + 1 < 16) stage(kb + 1);
    const char* As = gbase + ((kb & 1) << 14);
    const char* Bs = As + 8192;
    __builtin_amdgcn_s_setprio(1);
#pragma unroll
    for (int ks = 0; ks < 2; ++ks) {
      const int kc = (ks << 2) + (ln >> 4);
      auto ld = [&](const char* base, int row) -> bf16x8 {
        return *(const bf16x8*)(base + row * 128 + ((kc ^ (row & 7)) << 4));
      };
      bf16x8 A0 = ld(As, wm + (ln & 15));
      bf16x8 A1 = ld(As, wm + 16 + (ln & 15));
      bf16x8 B0 = ld(Bs, wn + (ln & 15));
      bf16x8 B1 = ld(Bs, wn + 16 + (ln & 15));
      acc00 = MFMA16(A0, B0, acc00);
      acc01 = MFMA16(A0, B1, acc01);
      acc10 = MFMA16(A1, B0, acc10);
      acc11 = MFMA16(A1, B1, acc11);
    }
    __builtin_amdgcn_s_setprio(0);
  }

  __syncthreads();
  float* gs = (float*)smem;
#pragma unroll
  for (int mi = 0; mi < 2; ++mi)
#pragma unroll
    for (int ni = 0; ni < 2; ++ni) {
      f32x4 a = (mi == 0) ? (ni == 0 ? acc00 : acc01) : (ni == 0 ? acc10 : acc11);
#pragma unroll
      for (int r = 0; r < 4; ++r) {
        int row = wm + mi * 16 + ((ln >> 4) << 2) + r;
        int col = wn + ni * 16 + (ln & 15);
        gs[grp * 4352 + row * 68 + col] = a[r];
      }
    }
  __syncthreads();

  const int h = tid & 15, mr = tid >> 4;
  const int hg = (nt << 4) + h;
#pragma unroll
  for (int half = 0; half < 2; ++half) {
    int m = mr + (half << 5);
    int gm = m0 + m;
    float4 v = *(const float4*)(gs + m * 68 + (h << 2));
    float g0 = v.x, g1 = v.y, g2 = v.z, g3 = v.w;
    if (use2) {
      float4 u = *(const float4*)(gs + 4352 + m * 68 + (h << 2));
      g0 += u.x; g1 += u.y; g2 += u.z; g3 += u.w;
    }
    int nb = n0 + (h << 2);
    if (pe) { float4 pv = *(const float4*)(pe + (size_t)gm * 4096 + nb);
              g0 += pv.x; g1 += pv.y; g2 += pv.z; g3 += pv.w; }
    if (bias){ float4 bv = *(const float4*)(bias + nb);
              g0 += bv.x; g1 += bv.y; g2 += bv.z; g3 += bv.w; }
    if (bsub){ float4 sv = *(const float4*)(bsub + nb);
              g0 -= sv.x; g1 -= sv.y; g2 -= sv.z; g3 -= sv.w; }
    float ig = sigm(g0), fg = sigm(g1), gg = ftanh(g2), og = sigm(g3);
    size_t idx = (size_t)gm * 1024 + hg;
    float cn = fg * c_in[idx] + ig * gg;
    c_out[idx] = cn;
    h_out[idx] = __float2bfloat16(og * ftanh(cn));
  }
}

// ---------------------------------------------------------------------------
// Generic 64x64-tile bf16 GEMM C = A @ W.T with epilogues (see round 1)
// ---------------------------------------------------------------------------
template <int EP>
__global__ __launch_bounds__(256) void gemm_ep(
    const bf16* __restrict__ A, const bf16* __restrict__ W, int K,
    const float* __restrict__ bias,
    float* __restrict__ f1, float* __restrict__ f2,
    bf16* __restrict__ o1, bf16* __restrict__ o2, int gt_base)
{
  __shared__ __attribute__((aligned(128))) char smem[32768];
  const int tid = threadIdx.x;
  const int wv = tid >> 6, ln = tid & 63;
  const int n0 = blockIdx.x << 6;
  const int m0 = blockIdx.y << 6;
  const int Nn = (int)(gridDim.x << 6);
  const int wm = (wv >> 1) << 5, wn = (wv & 1) << 5;
  const int nkb = K >> 6;

  f32x4 acc00{}, acc01{}, acc10{}, acc11{};

  auto stage = [&](int kb, int buf) {
    int k0 = kb << 6;
    char* As = smem + buf * 16384;
    char* Bs = As + 8192;
#pragma unroll
    for (int i = 0; i < 2; ++i) {
      int r = ((i << 2) + wv) * 8 + (ln >> 3);
      int sc = (ln & 7) ^ (r & 7);
      gload16((const char*)(A + (size_t)(m0 + r) * K + k0) + (sc << 4),
              As + (((i << 2) + wv) << 10));
      gload16((const char*)(W + (size_t)(n0 + r) * K + k0) + (sc << 4),
              Bs + (((i << 2) + wv) << 10));
    }
  };

  stage(0, 0);
  __syncthreads();
  for (int kb = 0; kb < nkb; ++kb) {
    int buf = kb & 1;
    if (kb + 1 < nkb) stage(kb + 1, buf ^ 1);
    const char* As = smem + buf * 16384;
    const char* Bs = As + 8192;
#pragma unroll
    for (int ks = 0; ks < 2; ++ks) {
      const int kc = (ks << 2) + (ln >> 4);
      auto ld = [&](const char* base, int row) -> bf16x8 {
        return *(const bf16x8*)(base + row * 128 + ((kc ^ (row & 7)) << 4));
      };
      bf16x8 A0 = ld(As, wm + (ln & 15));
      bf16x8 A1 = ld(As, wm + 16 + (ln & 15));
      bf16x8 B0 = ld(Bs, wn + (ln & 15));
      bf16x8 B1 = ld(Bs, wn + 16 + (ln & 15));
      acc00 = MFMA16(A0, B0, acc00);
      acc01 = MFMA16(A0, B1, acc01);
      acc10 = MFMA16(A1, B0, acc10);
      acc11 = MFMA16(A1, B1, acc11);
    }
    __syncthreads();
  }

#pragma unroll
  for (int mi = 0; mi < 2; ++mi)
#pragma unroll
    for (int ni = 0; ni < 2; ++ni) {
      f32x4 a = (mi == 0) ? (ni == 0 ? acc00 : acc01) : (ni == 0 ? acc10 : acc11);
#pragma unroll
      for (int r = 0; r < 4; ++r) {
        int m = m0 + wm + mi * 16 + ((ln >> 4) << 2) + r;
        int n = n0 + wn + ni * 16 + (ln & 15);
        float v = a[r];
        if constexpr (EP == 0) {
          o1[(size_t)m * Nn + n] = __float2bfloat16(v);
        } else if constexpr (EP == 1) {
          v = tanhf(v + bias[n]);
          int q = n >> 10, hh = n & 1023;
          size_t idx = (size_t)m * 1024 + hh;
          if (q == 0)      o1[idx] = __float2bfloat16(v);
          else if (q == 1) o2[idx] = __float2bfloat16(v);
          else if (q == 2) f1[idx] = v;
          else             f2[idx] = v;
        } else if constexpr (EP == 2) {
          f1[(size_t)m * 4096 + n] = v + bias[n];
        } else {
          int b = m & 255, g = (m >> 8) + gt_base;
          f1[(size_t)b * 131072 + (size_t)g * 512 + n] = v + bias[n];
        }
      }
    }
}

// ------------------------- small prep kernels ------------------------------
__global__ void k_conv(const float* __restrict__ s, bf16* __restrict__ d, int n) {
  int i = blockIdx.x * 256 + threadIdx.x;
  if (i < n) d[i] = __float2bfloat16(s[i]);
}
__global__ void k_trans_wout(const float* __restrict__ s, bf16* __restrict__ d) {
  int i = blockIdx.x * 256 + threadIdx.x;
  int l = i >> 9, j = i & 511;
  d[i] = __float2bfloat16(s[(size_t)j * 1024 + l]);
}
__global__ void k_reorder_g(const float* __restrict__ s, bf16* __restrict__ d) {
  int i = blockIdx.x * 256 + threadIdx.x;
  int np = i >> 10, kx = i & 1023;
  int hh = np >> 2, q = np & 3;
  d[i] = __float2bfloat16(s[(size_t)(q * 1024 + hh) * 1024 + kx]);
}
__global__ void k_reorder_c(const float* __restrict__ s, bf16* __restrict__ d, int coloff) {
  int i = blockIdx.x * 256 + threadIdx.x;
  int np = i >> 9, kx = i & 511;
  int hh = np >> 2, q = np & 3;
  d[i] = __float2bfloat16(s[(size_t)(q * 1024 + hh) * 1024 + coloff + kx]);
}
__global__ void k_bias(const float* __restrict__ bih1, const float* __restrict__ bhh1,
                       const float* __restrict__ bih2, const float* __restrict__ bhh2,
                       const float* __restrict__ bo,   const float* __restrict__ Wih1,
                       float* __restrict__ b1r, float* __restrict__ b2r,
                       float* __restrict__ bfr) {
  int n = blockIdx.x * 256 + threadIdx.x;
  int hh = n >> 2, q = n & 3, r = q * 1024 + hh;
  const float* wrow = Wih1 + (size_t)r * 1024 + 512;
  float acc = 0.f;
  for (int j = 0; j < 512; ++j) acc += bo[j] * wrow[j];
  bfr[n] = acc;
  b1r[n] = bih1[r] + bhh1[r] + acc;
  b2r[n] = bih2[r] + bhh2[r];
}
__global__ void k_ratio(float* __restrict__ dst, const int* __restrict__ ep,
                        const int* __restrict__ kv) {
  float kf = (float)kv[0];
  dst[0] = kf / (kf + __expf((float)ep[0] / kf));
}
__global__ void k_zero(unsigned* __restrict__ p) {
  if (threadIdx.x < 64) p[threadIdx.x] = 0u;
}

// ---------------------------------------------------------------------------
extern "C" void kernel_launch(void* const* d_in, const int* in_sizes, int n_in,
                              void* d_out, int out_size, void* d_ws, size_t ws_size,
                              hipStream_t stream) {
  (void)in_sizes; (void)n_in;
  const float* in_c     = (const float*)d_in[0];
  const float* in_Winit = (const float*)d_in[1];
  const float* in_binit = (const float*)d_in[2];
  const float* in_Wih1  = (const float*)d_in[3];
  const float* in_Whh1  = (const float*)d_in[4];
  const float* in_bih1  = (const float*)d_in[5];
  const float* in_bhh1  = (const float*)d_in[6];
  const float* in_Wih2  = (const float*)d_in[7];
  const float* in_Whh2  = (const float*)d_in[8];
  const float* in_bih2  = (const float*)d_in[9];
  const float* in_bhh2  = (const float*)d_in[10];
  const float* in_Wout  = (const float*)d_in[11];
  const float* in_bout  = (const float*)d_in[12];
  const int*   in_epoch = (const int*)d_in[14];
  const int*   in_k     = (const int*)d_in[15];
  float* out = (float*)d_out;

  char* p = (char*)d_ws;
  auto alloc = [&](size_t bytes) { char* q = p; p += (bytes + 255) & ~(size_t)255; return q; };
  bf16* wHH1  = (bf16*)alloc(4096ull * 1024 * 2);
  bf16* wFOLD = (bf16*)alloc(4096ull * 1024 * 2);
  bf16* wIH2  = (bf16*)alloc(4096ull * 1024 * 2);
  bf16* wHH2  = (bf16*)alloc(4096ull * 1024 * 2);
  bf16* wOUT  = (bf16*)alloc(512ull * 1024 * 2);
  bf16* wOUTT = (bf16*)alloc(1024ull * 512 * 2);
  bf16* wINIT = (bf16*)alloc(4096ull * 512 * 2);
  bf16* wIH1C = (bf16*)alloc(4096ull * 512 * 2);
  bf16* wPREV = (bf16*)alloc(4096ull * 512 * 2);
  bf16* cbf   = (bf16*)alloc(4096ull * 512 * 2);
  float* b1r  = (float*)alloc(4096 * 4);
  float* b2r  = (float*)alloc(4096 * 4);
  float* bfr  = (float*)alloc(4096 * 4);
  unsigned* bar = (unsigned*)alloc(4096);
  bf16* h1i   = (bf16*)alloc(16ull * 256 * 1024 * 2);
  bf16* h2i   = (bf16*)alloc(16ull * 256 * 1024 * 2);
  float* c1i  = (float*)alloc(16ull * 256 * 1024 * 4);
  float* c2i  = (float*)alloc(16ull * 256 * 1024 * 4);
  float* PE1  = (float*)alloc(16ull * 256 * 4096 * 4);
  bf16* h1b[2]; float* c1b[2]; float* c2b[2]; bf16* h2b[2];
  for (int i = 0; i < 2; ++i) {
    h1b[i] = (bf16*)alloc(256ull * 1024 * 2);
    c1b[i] = (float*)alloc(256ull * 1024 * 4);
    c2b[i] = (float*)alloc(256ull * 1024 * 4);
    h2b[i] = (bf16*)alloc(256ull * 1024 * 2);
  }
  bf16* h1ring = (bf16*)alloc((size_t)RD * 256 * 1024 * 2);
  size_t need_nohist = (size_t)(p - (char*)d_ws);
  bf16* hist = (bf16*)alloc(256ull * 256 * 1024 * 2);
  size_t need_full = (size_t)(p - (char*)d_ws);
  bool persist = ws_size >= need_full;
  bool primary = ws_size >= need_full;  // hist-based output path
  (void)need_nohist;

  // ---- prep ----
  k_conv<<<8192, 256, 0, stream>>>(in_c, cbf, 2097152);
  k_conv<<<2048, 256, 0, stream>>>(in_Wout, wOUT, 524288);
  k_conv<<<8192, 256, 0, stream>>>(in_Winit, wINIT, 2097152);
  k_trans_wout<<<2048, 256, 0, stream>>>(in_Wout, wOUTT);
  k_reorder_g<<<16384, 256, 0, stream>>>(in_Whh1, wHH1);
  k_reorder_g<<<16384, 256, 0, stream>>>(in_Wih2, wIH2);
  k_reorder_g<<<16384, 256, 0, stream>>>(in_Whh2, wHH2);
  k_reorder_c<<<8192, 256, 0, stream>>>(in_Wih1, wIH1C, 0);
  k_reorder_c<<<8192, 256, 0, stream>>>(in_Wih1, wPREV, 512);
  k_bias<<<16, 256, 0, stream>>>(in_bih1, in_bhh1, in_bih2, in_bhh2, in_bout,
                                 in_Wih1, b1r, b2r, bfr);
  k_zero<<<1, 64, 0, stream>>>(bar);
  gemm_ep<0><<<dim3(16, 64), 256, 0, stream>>>(wPREV, wOUTT, 512, nullptr,
                                               nullptr, nullptr, wFOLD, nullptr, 0);
  gemm_ep<1><<<dim3(64, 64), 256, 0, stream>>>(cbf, wINIT, 512, in_binit,
                                               c1i, c2i, h1i, h2i, 0);
  gemm_ep<2><<<dim3(64, 64), 256, 0, stream>>>(cbf, wIH1C, 512, b1r,
                                               PE1, nullptr, nullptr, nullptr, 0);

  const size_t S = 256ull * 1024;
  if (persist) {
    // ---- one persistent kernel for all 512 recurrent GEMMs ----
    rnn_persist<<<256, 512, 0, stream>>>(wHH1, wFOLD, wIH2, wHH2, PE1, b2r, bfr,
                                         h1i, h2i, c1i, c2i, h1ring, hist, bar);
    gemm_ep<3><<<dim3(8, 1024), 256, 0, stream>>>(hist, wOUT, 1024, in_bout,
                                                  out, nullptr, nullptr, nullptr, 0);
  } else {
    // ---- fallback: launch-per-step (round-2 path) ----
    for (int s = 0; s < 16; ++s) {
      for (int t = 0; t < 16; ++t) {
        int gt = s * 16 + t;
        int cur = gt & 1, prv = cur ^ 1;
        const bf16* h2prev = (gt == 0) ? nullptr
                            : (primary ? hist + (size_t)(gt - 1) * S : h2b[prv]);
        rnn_step<<<dim3(64, 4), 512, 0, stream>>>(
            (t == 0) ? h1i + (size_t)s * S : h1b[prv], h2prev,
            wHH1, wFOLD,
            PE1 + (size_t)s * 1048576, nullptr, (gt == 0) ? bfr : nullptr,
            (t == 0) ? c1i + (size_t)s * S : c1b[prv], c1b[cur], h1b[cur]);
        rnn_step<<<dim3(64, 4), 512, 0, stream>>>(
            h1b[cur],
            (t == 0) ? h2i + (size_t)s * S
                     : (primary ? hist + (size_t)(gt - 1) * S : h2b[prv]),
            wIH2, wHH2, nullptr, b2r, nullptr,
            (t == 0) ? c2i + (size_t)s * S : c2b[prv], c2b[cur],
            primary ? hist + (size_t)gt * S : h2b[cur]);
        if (!primary) {
          gemm_ep<3><<<dim3(8, 4), 256, 0, stream>>>(h2b[cur], wOUT, 1024, in_bout,
                                                     out, nullptr, nullptr, nullptr, gt);
        }
      }
    }
    if (primary) {
      gemm_ep<3><<<dim3(8, 1024), 256, 0, stream>>>(hist, wOUT, 1024, in_bout,
                                                    out, nullptr, nullptr, nullptr, 0);
    }
  }
  k_ratio<<<1, 1, 0, stream>>>(out + (out_size - 1), in_epoch, in_k);
}

// Round 4
// 6607.757 us; speedup vs baseline: 1.1925x; 1.1925x over previous
//
#include <hip/hip_runtime.h>
#include <hip/hip_bf16.h>

using bf16 = __hip_bfloat16;
typedef __attribute__((ext_vector_type(8))) short bf16x8;
typedef __attribute__((ext_vector_type(4))) float f32x4;

__device__ __forceinline__ void gload16(const void* g, void* l) {
  __builtin_amdgcn_global_load_lds((const __attribute__((address_space(1))) void*)g,
                                   (__attribute__((address_space(3))) void*)l, 16, 0, 0);
}

__device__ __forceinline__ float sigm(float x) { return 1.0f / (1.0f + __expf(-x)); }
// overflow-safe fast tanh
__device__ __forceinline__ float ftanh(float x) {
  float e = __expf(2.0f * fabsf(x));
  return copysignf(1.0f - 2.0f / (e + 1.0f), x);
}

#define MFMA16(a, b, c) __builtin_amdgcn_mfma_f32_16x16x32_bf16(a, b, c, 0, 0, 0)
#define WAITV2() asm volatile("s_waitcnt vmcnt(2)" ::: "memory")
#define WAITV0() asm volatile("s_waitcnt vmcnt(0)" ::: "memory")
#define BARRIER() do { __builtin_amdgcn_s_barrier(); asm volatile("" ::: "memory"); } while (0)

struct Frag { bf16x8 a0, a1, b0, b1; };

// ---------------------------------------------------------------------------
// Recurrent step GEMM: g[256,4096] = pe + a1@w1.T + a2@w2.T (+bias -bsub),
// fused LSTM-gate epilogue (weights gate-interleaved: col n = 4*h + q).
// 512 threads: wave-group 0 (waves 0-3) does a1@w1 (K=1024), group 1 a2@w2.
// K-loop: BK=32, 4 LDS buffers/group, depth-2 prefetch with counted vmcnt(2)
// (loads stay in flight across s_barrier), register frag double-buffer.
// grid 256 linear (XCD-decoded), block 512.
// ---------------------------------------------------------------------------
__global__ __launch_bounds__(512) void rnn_step(
    const bf16* __restrict__ a1, const bf16* __restrict__ a2,
    const bf16* __restrict__ w1, const bf16* __restrict__ w2,
    const float* __restrict__ pe, const float* __restrict__ bias,
    const float* __restrict__ bsub,
    const float* __restrict__ c_in, float* __restrict__ c_out,
    bf16* __restrict__ h_out)
{
  __shared__ __attribute__((aligned(128))) char smem[65536];
  const int tid = threadIdx.x;
  const int wv = tid >> 6, ln = tid & 63;
  const int grp = wv >> 2, wg = wv & 3;
  // XCD-aware decode: blocks sharing a B-panel (same nt) land on one XCD,
  // and each XCD owns a contiguous range of 8 nt values.
  const int bid = blockIdx.x;
  const int nt = ((bid & 7) << 3) | ((bid >> 3) & 7);
  const int mt = bid >> 6;
  const int m0 = mt << 6, n0 = nt << 6;
  const int wm = (wg >> 1) << 5, wn = (wg & 1) << 5;
  const bool use2 = (a2 != nullptr);

  const bf16* asrc = (grp == 0) ? a1 : (use2 ? a2 : a1);
  const bf16* wsrc = (grp == 0) ? w1 : (use2 ? w2 : w1);
  char* gbase = smem + (grp << 15);  // 32KB/group: 4 bufs x (4KB A + 4KB B)

  // ---- staging geometry (write side): lane -> (row, phys chunk) linear ----
  const int srow = (wg << 4) + (ln >> 2);          // tile row 0..63
  const int skc  = (ln & 3) ^ ((srow >> 1) & 3);   // logical k-chunk for this slot
  const size_t aGOff = ((size_t)(m0 + srow) << 11) + (skc << 4);
  const size_t bGOff = ((size_t)(n0 + srow) << 11) + (skc << 4);

  auto stage = [&](int kb) {
    char* dst = gbase + ((kb & 3) << 13) + (wg << 10);
    gload16((const char*)asrc + aGOff + ((size_t)kb << 6), dst);
    gload16((const char*)wsrc + bGOff + ((size_t)kb << 6), dst + 4096);
  };

  // ---- read-side offsets (per-lane constants) ----
  const int kc = ln >> 4;
  const int ar0 = wm + (ln & 15), ar1 = ar0 + 16;
  const int br0 = wn + (ln & 15), br1 = br0 + 16;
  const int aoff0 = ar0 * 64 + ((kc ^ ((ar0 >> 1) & 3)) << 4);
  const int aoff1 = ar1 * 64 + ((kc ^ ((ar1 >> 1) & 3)) << 4);
  const int boff0 = 4096 + br0 * 64 + ((kc ^ ((br0 >> 1) & 3)) << 4);
  const int boff1 = 4096 + br1 * 64 + ((kc ^ ((br1 >> 1) & 3)) << 4);

  auto ldfrags = [&](int kb, Frag& f) {
    const char* base = gbase + ((kb & 3) << 13);
    f.a0 = *(const bf16x8*)(base + aoff0);
    f.a1 = *(const bf16x8*)(base + aoff1);
    f.b0 = *(const bf16x8*)(base + boff0);
    f.b1 = *(const bf16x8*)(base + boff1);
  };

  f32x4 acc00{}, acc01{}, acc10{}, acc11{};
  auto domfma = [&](Frag& f) {
    acc00 = MFMA16(f.a0, f.b0, acc00);
    acc01 = MFMA16(f.a0, f.b1, acc01);
    acc10 = MFMA16(f.a1, f.b0, acc10);
    acc11 = MFMA16(f.a1, f.b1, acc11);
  };

  Frag f0, f1;
  // prologue
  stage(0); stage(1);
  WAITV2(); BARRIER();
  stage(2);
  ldfrags(0, f0);
  __builtin_amdgcn_s_setprio(1);
  // main loop: 15 unrolled pairs covering kb = 1..30
  for (int kb = 1; kb < 31; kb += 2) {
    WAITV2(); BARRIER();
    stage(kb + 2);
    ldfrags(kb, f1);
    domfma(f0);
    WAITV2(); BARRIER();
    if (kb + 3 < 32) stage(kb + 3);
    ldfrags(kb + 1, f0);
    domfma(f1);
  }
  // peel kb = 31
  WAITV0(); BARRIER();
  ldfrags(31, f1);
  domfma(f0);
  domfma(f1);
  __builtin_amdgcn_s_setprio(0);

  // ---- epilogue: gather 4 gates per (batch,hidden), LSTM nonlinearity ----
  __syncthreads();
  float* gs = (float*)smem;  // [2][64][68]
#pragma unroll
  for (int mi = 0; mi < 2; ++mi)
#pragma unroll
    for (int ni = 0; ni < 2; ++ni) {
      f32x4 a = (mi == 0) ? (ni == 0 ? acc00 : acc01) : (ni == 0 ? acc10 : acc11);
#pragma unroll
      for (int r = 0; r < 4; ++r) {
        int row = wm + mi * 16 + ((ln >> 4) << 2) + r;
        int col = wn + ni * 16 + (ln & 15);
        gs[grp * 4352 + row * 68 + col] = a[r];
      }
    }
  __syncthreads();

  const int h = tid & 15, mr = tid >> 4;
  const int hg = (nt << 4) + h;
#pragma unroll
  for (int half = 0; half < 2; ++half) {
    int m = mr + (half << 5);
    int gm = m0 + m;
    float4 v = *(const float4*)(gs + m * 68 + (h << 2));
    float g0 = v.x, g1 = v.y, g2 = v.z, g3 = v.w;
    if (use2) {
      float4 u = *(const float4*)(gs + 4352 + m * 68 + (h << 2));
      g0 += u.x; g1 += u.y; g2 += u.z; g3 += u.w;
    }
    int nb = n0 + (h << 2);
    if (pe) { float4 pv = *(const float4*)(pe + (size_t)gm * 4096 + nb);
              g0 += pv.x; g1 += pv.y; g2 += pv.z; g3 += pv.w; }
    if (bias){ float4 bv = *(const float4*)(bias + nb);
              g0 += bv.x; g1 += bv.y; g2 += bv.z; g3 += bv.w; }
    if (bsub){ float4 sv = *(const float4*)(bsub + nb);
              g0 -= sv.x; g1 -= sv.y; g2 -= sv.z; g3 -= sv.w; }
    float ig = sigm(g0), fg = sigm(g1), gg = ftanh(g2), og = sigm(g3);
    size_t idx = (size_t)gm * 1024 + hg;
    float cn = fg * c_in[idx] + ig * gg;
    c_out[idx] = cn;
    h_out[idx] = __float2bfloat16(og * ftanh(cn));
  }
}

// ---------------------------------------------------------------------------
// Generic 64x64-tile bf16 GEMM C = A @ W.T with epilogues:
// EP0: store bf16 to o1[M][N]            (W_fold build)
// EP1: tanh(v+bias[n]) routed into h1i/h2i (bf16) | c1i/c2i (f32) quadrants
// EP2: f1[m*4096+n] = v + bias[n]        (PE build)
// EP3: f1[b*131072 + gt*512 + n] = v + bias[n], m = gt_local*256+b (outputs)
// ---------------------------------------------------------------------------
template <int EP>
__global__ __launch_bounds__(256) void gemm_ep(
    const bf16* __restrict__ A, const bf16* __restrict__ W, int K,
    const float* __restrict__ bias,
    float* __restrict__ f1, float* __restrict__ f2,
    bf16* __restrict__ o1, bf16* __restrict__ o2, int gt_base)
{
  __shared__ __attribute__((aligned(128))) char smem[32768];
  const int tid = threadIdx.x;
  const int wv = tid >> 6, ln = tid & 63;
  const int n0 = blockIdx.x << 6;
  const int m0 = blockIdx.y << 6;
  const int Nn = (int)(gridDim.x << 6);
  const int wm = (wv >> 1) << 5, wn = (wv & 1) << 5;
  const int nkb = K >> 6;

  f32x4 acc00{}, acc01{}, acc10{}, acc11{};

  auto stage = [&](int kb, int buf) {
    int k0 = kb << 6;
    char* As = smem + buf * 16384;
    char* Bs = As + 8192;
#pragma unroll
    for (int i = 0; i < 2; ++i) {
      int r = ((i << 2) + wv) * 8 + (ln >> 3);
      int sc = (ln & 7) ^ (r & 7);
      gload16((const char*)(A + (size_t)(m0 + r) * K + k0) + (sc << 4),
              As + (((i << 2) + wv) << 10));
      gload16((const char*)(W + (size_t)(n0 + r) * K + k0) + (sc << 4),
              Bs + (((i << 2) + wv) << 10));
    }
  };

  stage(0, 0);
  __syncthreads();
  for (int kb = 0; kb < nkb; ++kb) {
    int buf = kb & 1;
    if (kb + 1 < nkb) stage(kb + 1, buf ^ 1);
    const char* As = smem + buf * 16384;
    const char* Bs = As + 8192;
#pragma unroll
    for (int ks = 0; ks < 2; ++ks) {
      const int kc = (ks << 2) + (ln >> 4);
      auto ld = [&](const char* base, int row) -> bf16x8 {
        return *(const bf16x8*)(base + row * 128 + ((kc ^ (row & 7)) << 4));
      };
      bf16x8 A0 = ld(As, wm + (ln & 15));
      bf16x8 A1 = ld(As, wm + 16 + (ln & 15));
      bf16x8 B0 = ld(Bs, wn + (ln & 15));
      bf16x8 B1 = ld(Bs, wn + 16 + (ln & 15));
      acc00 = MFMA16(A0, B0, acc00);
      acc01 = MFMA16(A0, B1, acc01);
      acc10 = MFMA16(A1, B0, acc10);
      acc11 = MFMA16(A1, B1, acc11);
    }
    __syncthreads();
  }

#pragma unroll
  for (int mi = 0; mi < 2; ++mi)
#pragma unroll
    for (int ni = 0; ni < 2; ++ni) {
      f32x4 a = (mi == 0) ? (ni == 0 ? acc00 : acc01) : (ni == 0 ? acc10 : acc11);
#pragma unroll
      for (int r = 0; r < 4; ++r) {
        int m = m0 + wm + mi * 16 + ((ln >> 4) << 2) + r;
        int n = n0 + wn + ni * 16 + (ln & 15);
        float v = a[r];
        if constexpr (EP == 0) {
          o1[(size_t)m * Nn + n] = __float2bfloat16(v);
        } else if constexpr (EP == 1) {
          v = tanhf(v + bias[n]);
          int q = n >> 10, hh = n & 1023;
          size_t idx = (size_t)m * 1024 + hh;
          if (q == 0)      o1[idx] = __float2bfloat16(v);
          else if (q == 1) o2[idx] = __float2bfloat16(v);
          else if (q == 2) f1[idx] = v;
          else             f2[idx] = v;
        } else if constexpr (EP == 2) {
          f1[(size_t)m * 4096 + n] = v + bias[n];
        } else {
          int b = m & 255, g = (m >> 8) + gt_base;
          f1[(size_t)b * 131072 + (size_t)g * 512 + n] = v + bias[n];
        }
      }
    }
}

// ------------------------- small prep kernels ------------------------------
__global__ void k_conv(const float* __restrict__ s, bf16* __restrict__ d, int n) {
  int i = blockIdx.x * 256 + threadIdx.x;
  if (i < n) d[i] = __float2bfloat16(s[i]);
}
__global__ void k_trans_wout(const float* __restrict__ s, bf16* __restrict__ d) {
  int i = blockIdx.x * 256 + threadIdx.x;
  int l = i >> 9, j = i & 511;
  d[i] = __float2bfloat16(s[(size_t)j * 1024 + l]);
}
__global__ void k_reorder_g(const float* __restrict__ s, bf16* __restrict__ d) {
  int i = blockIdx.x * 256 + threadIdx.x;
  int np = i >> 10, kx = i & 1023;
  int hh = np >> 2, q = np & 3;
  d[i] = __float2bfloat16(s[(size_t)(q * 1024 + hh) * 1024 + kx]);
}
__global__ void k_reorder_c(const float* __restrict__ s, bf16* __restrict__ d, int coloff) {
  int i = blockIdx.x * 256 + threadIdx.x;
  int np = i >> 9, kx = i & 511;
  int hh = np >> 2, q = np & 3;
  d[i] = __float2bfloat16(s[(size_t)(q * 1024 + hh) * 1024 + coloff + kx]);
}
__global__ void k_bias(const float* __restrict__ bih1, const float* __restrict__ bhh1,
                       const float* __restrict__ bih2, const float* __restrict__ bhh2,
                       const float* __restrict__ bo,   const float* __restrict__ Wih1,
                       float* __restrict__ b1r, float* __restrict__ b2r,
                       float* __restrict__ bfr) {
  int n = blockIdx.x * 256 + threadIdx.x;
  int hh = n >> 2, q = n & 3, r = q * 1024 + hh;
  const float* wrow = Wih1 + (size_t)r * 1024 + 512;
  float acc = 0.f;
  for (int j = 0; j < 512; ++j) acc += bo[j] * wrow[j];
  bfr[n] = acc;
  b1r[n] = bih1[r] + bhh1[r] + acc;
  b2r[n] = bih2[r] + bhh2[r];
}
__global__ void k_ratio(float* __restrict__ dst, const int* __restrict__ ep,
                        const int* __restrict__ kv) {
  float kf = (float)kv[0];
  dst[0] = kf / (kf + __expf((float)ep[0] / kf));
}

// ---------------------------------------------------------------------------
extern "C" void kernel_launch(void* const* d_in, const int* in_sizes, int n_in,
                              void* d_out, int out_size, void* d_ws, size_t ws_size,
                              hipStream_t stream) {
  (void)in_sizes; (void)n_in;
  const float* in_c     = (const float*)d_in[0];
  const float* in_Winit = (const float*)d_in[1];
  const float* in_binit = (const float*)d_in[2];
  const float* in_Wih1  = (const float*)d_in[3];
  const float* in_Whh1  = (const float*)d_in[4];
  const float* in_bih1  = (const float*)d_in[5];
  const float* in_bhh1  = (const float*)d_in[6];
  const float* in_Wih2  = (const float*)d_in[7];
  const float* in_Whh2  = (const float*)d_in[8];
  const float* in_bih2  = (const float*)d_in[9];
  const float* in_bhh2  = (const float*)d_in[10];
  const float* in_Wout  = (const float*)d_in[11];
  const float* in_bout  = (const float*)d_in[12];
  const int*   in_epoch = (const int*)d_in[14];
  const int*   in_k     = (const int*)d_in[15];
  float* out = (float*)d_out;

  char* p = (char*)d_ws;
  auto alloc = [&](size_t bytes) { char* q = p; p += (bytes + 255) & ~(size_t)255; return q; };
  bf16* wHH1  = (bf16*)alloc(4096ull * 1024 * 2);
  bf16* wFOLD = (bf16*)alloc(4096ull * 1024 * 2);
  bf16* wIH2  = (bf16*)alloc(4096ull * 1024 * 2);
  bf16* wHH2  = (bf16*)alloc(4096ull * 1024 * 2);
  bf16* wOUT  = (bf16*)alloc(512ull * 1024 * 2);
  bf16* wOUTT = (bf16*)alloc(1024ull * 512 * 2);
  bf16* wINIT = (bf16*)alloc(4096ull * 512 * 2);
  bf16* wIH1C = (bf16*)alloc(4096ull * 512 * 2);
  bf16* wPREV = (bf16*)alloc(4096ull * 512 * 2);
  bf16* cbf   = (bf16*)alloc(4096ull * 512 * 2);
  float* b1r  = (float*)alloc(4096 * 4);
  float* b2r  = (float*)alloc(4096 * 4);
  float* bfr  = (float*)alloc(4096 * 4);
  bf16* h1i   = (bf16*)alloc(16ull * 256 * 1024 * 2);
  bf16* h2i   = (bf16*)alloc(16ull * 256 * 1024 * 2);
  float* c1i  = (float*)alloc(16ull * 256 * 1024 * 4);
  float* c2i  = (float*)alloc(16ull * 256 * 1024 * 4);
  float* PE1  = (float*)alloc(16ull * 256 * 4096 * 4);
  bf16* h1b[2]; float* c1b[2]; float* c2b[2]; bf16* h2b[2];
  for (int i = 0; i < 2; ++i) {
    h1b[i] = (bf16*)alloc(256ull * 1024 * 2);
    c1b[i] = (float*)alloc(256ull * 1024 * 4);
    c2b[i] = (float*)alloc(256ull * 1024 * 4);
    h2b[i] = (bf16*)alloc(256ull * 1024 * 2);
  }
  bf16* hist = (bf16*)alloc(256ull * 256 * 1024 * 2);
  size_t need_full = (size_t)(p - (char*)d_ws);
  bool primary = ws_size >= need_full;

  // ---- prep ----
  k_conv<<<8192, 256, 0, stream>>>(in_c, cbf, 2097152);
  k_conv<<<2048, 256, 0, stream>>>(in_Wout, wOUT, 524288);
  k_conv<<<8192, 256, 0, stream>>>(in_Winit, wINIT, 2097152);
  k_trans_wout<<<2048, 256, 0, stream>>>(in_Wout, wOUTT);
  k_reorder_g<<<16384, 256, 0, stream>>>(in_Whh1, wHH1);
  k_reorder_g<<<16384, 256, 0, stream>>>(in_Wih2, wIH2);
  k_reorder_g<<<16384, 256, 0, stream>>>(in_Whh2, wHH2);
  k_reorder_c<<<8192, 256, 0, stream>>>(in_Wih1, wIH1C, 0);
  k_reorder_c<<<8192, 256, 0, stream>>>(in_Wih1, wPREV, 512);
  k_bias<<<16, 256, 0, stream>>>(in_bih1, in_bhh1, in_bih2, in_bhh2, in_bout,
                                 in_Wih1, b1r, b2r, bfr);
  gemm_ep<0><<<dim3(16, 64), 256, 0, stream>>>(wPREV, wOUTT, 512, nullptr,
                                               nullptr, nullptr, wFOLD, nullptr, 0);
  gemm_ep<1><<<dim3(64, 64), 256, 0, stream>>>(cbf, wINIT, 512, in_binit,
                                               c1i, c2i, h1i, h2i, 0);
  gemm_ep<2><<<dim3(64, 64), 256, 0, stream>>>(cbf, wIH1C, 512, b1r,
                                               PE1, nullptr, nullptr, nullptr, 0);

  // ---- recurrence: 16 segments x 16 steps, 2 GEMM launches each ----
  const size_t S = 256ull * 1024;
  for (int s = 0; s < 16; ++s) {
    for (int t = 0; t < 16; ++t) {
      int gt = s * 16 + t;
      int cur = gt & 1, prv = cur ^ 1;
      const bf16* h2prev = (gt == 0) ? nullptr
                          : (primary ? hist + (size_t)(gt - 1) * S : h2b[prv]);
      // layer 1: g1 = PE1[s] + h1@W_hh1' + h2prev@W_fold'  (-b_fold at gt==0)
      rnn_step<<<256, 512, 0, stream>>>(
          (t == 0) ? h1i + (size_t)s * S : h1b[prv], h2prev,
          wHH1, wFOLD,
          PE1 + (size_t)s * 1048576, nullptr, (gt == 0) ? bfr : nullptr,
          (t == 0) ? c1i + (size_t)s * S : c1b[prv], c1b[cur], h1b[cur]);
      // layer 2: g2 = h1n@W_ih2' + h2@W_hh2' + b2
      rnn_step<<<256, 512, 0, stream>>>(
          h1b[cur],
          (t == 0) ? h2i + (size_t)s * S
                   : (primary ? hist + (size_t)(gt - 1) * S : h2b[prv]),
          wIH2, wHH2, nullptr, b2r, nullptr,
          (t == 0) ? c2i + (size_t)s * S : c2b[prv], c2b[cur],
          primary ? hist + (size_t)gt * S : h2b[cur]);
      if (!primary) {
        gemm_ep<3><<<dim3(8, 4), 256, 0, stream>>>(h2b[cur], wOUT, 1024, in_bout,
                                                   out, nullptr, nullptr, nullptr, gt);
      }
    }
  }

  // ---- outputs: one big GEMM over the h2 history ----
  if (primary) {
    gemm_ep<3><<<dim3(8, 1024), 256, 0, stream>>>(hist, wOUT, 1024, in_bout,
                                                  out, nullptr, nullptr, nullptr, 0);
  }
  k_ratio<<<1, 1, 0, stream>>>(out + (out_size - 1), in_epoch, in_k);
}

// Round 5
// 6140.673 us; speedup vs baseline: 1.2832x; 1.0761x over previous
//
#include <hip/hip_runtime.h>
#include <hip/hip_bf16.h>

using bf16 = __hip_bfloat16;
typedef __attribute__((ext_vector_type(8))) short bf16x8;
typedef __attribute__((ext_vector_type(4))) float f32x4;

__device__ __forceinline__ void gload16(const void* g, void* l) {
  __builtin_amdgcn_global_load_lds((const __attribute__((address_space(1))) void*)g,
                                   (__attribute__((address_space(3))) void*)l, 16, 0, 0);
}

__device__ __forceinline__ float sigm(float x) { return 1.0f / (1.0f + __expf(-x)); }
// overflow-safe fast tanh
__device__ __forceinline__ float ftanh(float x) {
  float e = __expf(2.0f * fabsf(x));
  return copysignf(1.0f - 2.0f / (e + 1.0f), x);
}

#define MFMA16(a, b, c) __builtin_amdgcn_mfma_f32_16x16x32_bf16(a, b, c, 0, 0, 0)
#define WAITV(n) asm volatile("s_waitcnt vmcnt(" #n ")" ::: "memory")
#define BARRIER() do { __builtin_amdgcn_s_barrier(); asm volatile("" ::: "memory"); } while (0)

struct Frag { bf16x8 a0, a1, b0, b1; };

// ---------------------------------------------------------------------------
// Recurrent step GEMM: g[256,4096] = pe + a1@w1.T + a2@w2.T (+bias -bsub),
// fused LSTM-gate epilogue (weights gate-interleaved: col n = 4*h + q).
// 512 threads: wave-group 0 (waves 0-3) does a1@w1 (K=1024), group 1 a2@w2.
// K-loop: BK=32, 8 LDS buffers/group (128KB LDS), prefetch depth 6 with
// counted vmcnt (loads stay in flight across s_barrier), barrier per kb-pair.
// grid 256 linear (XCD-decoded), block 512.
// ---------------------------------------------------------------------------
__global__ __launch_bounds__(512) void rnn_step(
    const bf16* __restrict__ a1, const bf16* __restrict__ a2,
    const bf16* __restrict__ w1, const bf16* __restrict__ w2,
    const float* __restrict__ pe, const float* __restrict__ bias,
    const float* __restrict__ bsub,
    const float* __restrict__ c_in, float* __restrict__ c_out,
    bf16* __restrict__ h_out)
{
  __shared__ __attribute__((aligned(128))) char smem[131072];
  const int tid = threadIdx.x;
  const int wv = tid >> 6, ln = tid & 63;
  const int grp = wv >> 2, wg = wv & 3;
  // XCD-aware decode: blocks sharing a B-panel (same nt) land on one XCD.
  const int bid = blockIdx.x;
  const int nt = ((bid & 7) << 3) | ((bid >> 3) & 7);
  const int mt = bid >> 6;
  const int m0 = mt << 6, n0 = nt << 6;
  const int wm = (wg >> 1) << 5, wn = (wg & 1) << 5;
  const bool use2 = (a2 != nullptr);

  const bf16* asrc = (grp == 0) ? a1 : (use2 ? a2 : a1);
  const bf16* wsrc = (grp == 0) ? w1 : (use2 ? w2 : w1);
  char* gbase = smem + (grp << 16);  // 64KB/group: 8 bufs x (4KB A + 4KB B)

  // ---- staging geometry (write side): lane -> (row, phys chunk) linear ----
  const int srow = (wg << 4) + (ln >> 2);          // tile row 0..63
  const int skc  = (ln & 3) ^ ((srow >> 1) & 3);   // pre-swizzled k-chunk
  const size_t aGOff = ((size_t)(m0 + srow) << 11) + (skc << 4);
  const size_t bGOff = ((size_t)(n0 + srow) << 11) + (skc << 4);

  auto stage = [&](int kb) {
    char* dst = gbase + ((kb & 7) << 13) + (wg << 10);
    gload16((const char*)asrc + aGOff + ((size_t)kb << 6), dst);
    gload16((const char*)wsrc + bGOff + ((size_t)kb << 6), dst + 4096);
  };

  // ---- read-side offsets (per-lane constants) ----
  const int kc = ln >> 4;
  const int ar0 = wm + (ln & 15), ar1 = ar0 + 16;
  const int br0 = wn + (ln & 15), br1 = br0 + 16;
  const int aoff0 = ar0 * 64 + ((kc ^ ((ar0 >> 1) & 3)) << 4);
  const int aoff1 = ar1 * 64 + ((kc ^ ((ar1 >> 1) & 3)) << 4);
  const int boff0 = 4096 + br0 * 64 + ((kc ^ ((br0 >> 1) & 3)) << 4);
  const int boff1 = 4096 + br1 * 64 + ((kc ^ ((br1 >> 1) & 3)) << 4);

  auto ldfrags = [&](int kb, Frag& f) {
    const char* base = gbase + ((kb & 7) << 13);
    f.a0 = *(const bf16x8*)(base + aoff0);
    f.a1 = *(const bf16x8*)(base + aoff1);
    f.b0 = *(const bf16x8*)(base + boff0);
    f.b1 = *(const bf16x8*)(base + boff1);
  };

  f32x4 acc00{}, acc01{}, acc10{}, acc11{};
  auto domfma = [&](Frag& f) {
    acc00 = MFMA16(f.a0, f.b0, acc00);
    acc01 = MFMA16(f.a0, f.b1, acc01);
    acc10 = MFMA16(f.a1, f.b0, acc10);
    acc11 = MFMA16(f.a1, f.b1, acc11);
  };

  Frag f0, f1;
  // ---- prologue: depth-6 prefetch (12 loads in flight) ----
  stage(0); stage(1); stage(2); stage(3); stage(4); stage(5);
  // pair 0 (kb 0,1): in-flight {0..5}=12; wait->8 => stage(0),(1) done
  WAITV(8); BARRIER();
  ldfrags(0, f0); ldfrags(1, f1);
  stage(6); stage(7);
  __builtin_amdgcn_s_setprio(1);
  domfma(f0); domfma(f1);
  __builtin_amdgcn_s_setprio(0);
  // pairs 1..13 (kb 2..27): steady-state
  for (int p = 1; p <= 13; ++p) {
    const int kb = p << 1;
    WAITV(8); BARRIER();
    ldfrags(kb, f0); ldfrags(kb + 1, f1);
    if (kb + 6 < 32) stage(kb + 6);
    if (kb + 7 < 32) stage(kb + 7);
    __builtin_amdgcn_s_setprio(1);
    domfma(f0); domfma(f1);
    __builtin_amdgcn_s_setprio(0);
  }
  // pair 14 (kb 28,29): in-flight {28..31}=8; wait->4 => 28,29 done
  WAITV(4); BARRIER();
  ldfrags(28, f0); ldfrags(29, f1);
  __builtin_amdgcn_s_setprio(1);
  domfma(f0); domfma(f1);
  __builtin_amdgcn_s_setprio(0);
  // pair 15 (kb 30,31): drain
  WAITV(0); BARRIER();
  ldfrags(30, f0); ldfrags(31, f1);
  __builtin_amdgcn_s_setprio(1);
  domfma(f0); domfma(f1);
  __builtin_amdgcn_s_setprio(0);

  // ---- epilogue: gather 4 gates per (batch,hidden), LSTM nonlinearity ----
  __syncthreads();
  float* gs = (float*)smem;  // [2][64][68]
#pragma unroll
  for (int mi = 0; mi < 2; ++mi)
#pragma unroll
    for (int ni = 0; ni < 2; ++ni) {
      f32x4 a = (mi == 0) ? (ni == 0 ? acc00 : acc01) : (ni == 0 ? acc10 : acc11);
#pragma unroll
      for (int r = 0; r < 4; ++r) {
        int row = wm + mi * 16 + ((ln >> 4) << 2) + r;
        int col = wn + ni * 16 + (ln & 15);
        gs[grp * 4352 + row * 68 + col] = a[r];
      }
    }
  __syncthreads();

  const int h = tid & 15, mr = tid >> 4;
  const int hg = (nt << 4) + h;
#pragma unroll
  for (int half = 0; half < 2; ++half) {
    int m = mr + (half << 5);
    int gm = m0 + m;
    float4 v = *(const float4*)(gs + m * 68 + (h << 2));
    float g0 = v.x, g1 = v.y, g2 = v.z, g3 = v.w;
    if (use2) {
      float4 u = *(const float4*)(gs + 4352 + m * 68 + (h << 2));
      g0 += u.x; g1 += u.y; g2 += u.z; g3 += u.w;
    }
    int nb = n0 + (h << 2);
    if (pe) { float4 pv = *(const float4*)(pe + (size_t)gm * 4096 + nb);
              g0 += pv.x; g1 += pv.y; g2 += pv.z; g3 += pv.w; }
    if (bias){ float4 bv = *(const float4*)(bias + nb);
              g0 += bv.x; g1 += bv.y; g2 += bv.z; g3 += bv.w; }
    if (bsub){ float4 sv = *(const float4*)(bsub + nb);
              g0 -= sv.x; g1 -= sv.y; g2 -= sv.z; g3 -= sv.w; }
    float ig = sigm(g0), fg = sigm(g1), gg = ftanh(g2), og = sigm(g3);
    size_t idx = (size_t)gm * 1024 + hg;
    float cn = fg * c_in[idx] + ig * gg;
    c_out[idx] = cn;
    h_out[idx] = __float2bfloat16(og * ftanh(cn));
  }
}

// ---------------------------------------------------------------------------
// Generic 64x64-tile bf16 GEMM C = A @ W.T with epilogues:
// EP0: store bf16 to o1[M][N]            (W_fold build)
// EP1: tanh(v+bias[n]) routed into h1i/h2i (bf16) | c1i/c2i (f32) quadrants
// EP2: f1[m*4096+n] = v + bias[n]        (PE build)
// EP3: f1[b*131072 + gt*512 + n] = v + bias[n], m = gt_local*256+b (outputs)
// ---------------------------------------------------------------------------
template <int EP>
__global__ __launch_bounds__(256) void gemm_ep(
    const bf16* __restrict__ A, const bf16* __restrict__ W, int K,
    const float* __restrict__ bias,
    float* __restrict__ f1, float* __restrict__ f2,
    bf16* __restrict__ o1, bf16* __restrict__ o2, int gt_base)
{
  __shared__ __attribute__((aligned(128))) char smem[32768];
  const int tid = threadIdx.x;
  const int wv = tid >> 6, ln = tid & 63;
  const int n0 = blockIdx.x << 6;
  const int m0 = blockIdx.y << 6;
  const int Nn = (int)(gridDim.x << 6);
  const int wm = (wv >> 1) << 5, wn = (wv & 1) << 5;
  const int nkb = K >> 6;

  f32x4 acc00{}, acc01{}, acc10{}, acc11{};

  auto stage = [&](int kb, int buf) {
    int k0 = kb << 6;
    char* As = smem + buf * 16384;
    char* Bs = As + 8192;
#pragma unroll
    for (int i = 0; i < 2; ++i) {
      int r = ((i << 2) + wv) * 8 + (ln >> 3);
      int sc = (ln & 7) ^ (r & 7);
      gload16((const char*)(A + (size_t)(m0 + r) * K + k0) + (sc << 4),
              As + (((i << 2) + wv) << 10));
      gload16((const char*)(W + (size_t)(n0 + r) * K + k0) + (sc << 4),
              Bs + (((i << 2) + wv) << 10));
    }
  };

  stage(0, 0);
  __syncthreads();
  for (int kb = 0; kb < nkb; ++kb) {
    int buf = kb & 1;
    if (kb + 1 < nkb) stage(kb + 1, buf ^ 1);
    const char* As = smem + buf * 16384;
    const char* Bs = As + 8192;
#pragma unroll
    for (int ks = 0; ks < 2; ++ks) {
      const int kc = (ks << 2) + (ln >> 4);
      auto ld = [&](const char* base, int row) -> bf16x8 {
        return *(const bf16x8*)(base + row * 128 + ((kc ^ (row & 7)) << 4));
      };
      bf16x8 A0 = ld(As, wm + (ln & 15));
      bf16x8 A1 = ld(As, wm + 16 + (ln & 15));
      bf16x8 B0 = ld(Bs, wn + (ln & 15));
      bf16x8 B1 = ld(Bs, wn + 16 + (ln & 15));
      acc00 = MFMA16(A0, B0, acc00);
      acc01 = MFMA16(A0, B1, acc01);
      acc10 = MFMA16(A1, B0, acc10);
      acc11 = MFMA16(A1, B1, acc11);
    }
    __syncthreads();
  }

#pragma unroll
  for (int mi = 0; mi < 2; ++mi)
#pragma unroll
    for (int ni = 0; ni < 2; ++ni) {
      f32x4 a = (mi == 0) ? (ni == 0 ? acc00 : acc01) : (ni == 0 ? acc10 : acc11);
#pragma unroll
      for (int r = 0; r < 4; ++r) {
        int m = m0 + wm + mi * 16 + ((ln >> 4) << 2) + r;
        int n = n0 + wn + ni * 16 + (ln & 15);
        float v = a[r];
        if constexpr (EP == 0) {
          o1[(size_t)m * Nn + n] = __float2bfloat16(v);
        } else if constexpr (EP == 1) {
          v = tanhf(v + bias[n]);
          int q = n >> 10, hh = n & 1023;
          size_t idx = (size_t)m * 1024 + hh;
          if (q == 0)      o1[idx] = __float2bfloat16(v);
          else if (q == 1) o2[idx] = __float2bfloat16(v);
          else if (q == 2) f1[idx] = v;
          else             f2[idx] = v;
        } else if constexpr (EP == 2) {
          f1[(size_t)m * 4096 + n] = v + bias[n];
        } else {
          int b = m & 255, g = (m >> 8) + gt_base;
          f1[(size_t)b * 131072 + (size_t)g * 512 + n] = v + bias[n];
        }
      }
    }
}

// ------------------------- small prep kernels ------------------------------
__global__ void k_conv(const float* __restrict__ s, bf16* __restrict__ d, int n) {
  int i = blockIdx.x * 256 + threadIdx.x;
  if (i < n) d[i] = __float2bfloat16(s[i]);
}
__global__ void k_trans_wout(const float* __restrict__ s, bf16* __restrict__ d) {
  int i = blockIdx.x * 256 + threadIdx.x;
  int l = i >> 9, j = i & 511;
  d[i] = __float2bfloat16(s[(size_t)j * 1024 + l]);
}
__global__ void k_reorder_g(const float* __restrict__ s, bf16* __restrict__ d) {
  int i = blockIdx.x * 256 + threadIdx.x;
  int np = i >> 10, kx = i & 1023;
  int hh = np >> 2, q = np & 3;
  d[i] = __float2bfloat16(s[(size_t)(q * 1024 + hh) * 1024 + kx]);
}
__global__ void k_reorder_c(const float* __restrict__ s, bf16* __restrict__ d, int coloff) {
  int i = blockIdx.x * 256 + threadIdx.x;
  int np = i >> 9, kx = i & 511;
  int hh = np >> 2, q = np & 3;
  d[i] = __float2bfloat16(s[(size_t)(q * 1024 + hh) * 1024 + coloff + kx]);
}
__global__ void k_bias(const float* __restrict__ bih1, const float* __restrict__ bhh1,
                       const float* __restrict__ bih2, const float* __restrict__ bhh2,
                       const float* __restrict__ bo,   const float* __restrict__ Wih1,
                       float* __restrict__ b1r, float* __restrict__ b2r,
                       float* __restrict__ bfr) {
  int n = blockIdx.x * 256 + threadIdx.x;
  int hh = n >> 2, q = n & 3, r = q * 1024 + hh;
  const float* wrow = Wih1 + (size_t)r * 1024 + 512;
  float acc = 0.f;
  for (int j = 0; j < 512; ++j) acc += bo[j] * wrow[j];
  bfr[n] = acc;
  b1r[n] = bih1[r] + bhh1[r] + acc;
  b2r[n] = bih2[r] + bhh2[r];
}
__global__ void k_ratio(float* __restrict__ dst, const int* __restrict__ ep,
                        const int* __restrict__ kv) {
  float kf = (float)kv[0];
  dst[0] = kf / (kf + __expf((float)ep[0] / kf));
}

// ---------------------------------------------------------------------------
extern "C" void kernel_launch(void* const* d_in, const int* in_sizes, int n_in,
                              void* d_out, int out_size, void* d_ws, size_t ws_size,
                              hipStream_t stream) {
  (void)in_sizes; (void)n_in;
  const float* in_c     = (const float*)d_in[0];
  const float* in_Winit = (const float*)d_in[1];
  const float* in_binit = (const float*)d_in[2];
  const float* in_Wih1  = (const float*)d_in[3];
  const float* in_Whh1  = (const float*)d_in[4];
  const float* in_bih1  = (const float*)d_in[5];
  const float* in_bhh1  = (const float*)d_in[6];
  const float* in_Wih2  = (const float*)d_in[7];
  const float* in_Whh2  = (const float*)d_in[8];
  const float* in_bih2  = (const float*)d_in[9];
  const float* in_bhh2  = (const float*)d_in[10];
  const float* in_Wout  = (const float*)d_in[11];
  const float* in_bout  = (const float*)d_in[12];
  const int*   in_epoch = (const int*)d_in[14];
  const int*   in_k     = (const int*)d_in[15];
  float* out = (float*)d_out;

  char* p = (char*)d_ws;
  auto alloc = [&](size_t bytes) { char* q = p; p += (bytes + 255) & ~(size_t)255; return q; };
  bf16* wHH1  = (bf16*)alloc(4096ull * 1024 * 2);
  bf16* wFOLD = (bf16*)alloc(4096ull * 1024 * 2);
  bf16* wIH2  = (bf16*)alloc(4096ull * 1024 * 2);
  bf16* wHH2  = (bf16*)alloc(4096ull * 1024 * 2);
  bf16* wOUT  = (bf16*)alloc(512ull * 1024 * 2);
  bf16* wOUTT = (bf16*)alloc(1024ull * 512 * 2);
  bf16* wINIT = (bf16*)alloc(4096ull * 512 * 2);
  bf16* wIH1C = (bf16*)alloc(4096ull * 512 * 2);
  bf16* wPREV = (bf16*)alloc(4096ull * 512 * 2);
  bf16* cbf   = (bf16*)alloc(4096ull * 512 * 2);
  float* b1r  = (float*)alloc(4096 * 4);
  float* b2r  = (float*)alloc(4096 * 4);
  float* bfr  = (float*)alloc(4096 * 4);
  bf16* h1i   = (bf16*)alloc(16ull * 256 * 1024 * 2);
  bf16* h2i   = (bf16*)alloc(16ull * 256 * 1024 * 2);
  float* c1i  = (float*)alloc(16ull * 256 * 1024 * 4);
  float* c2i  = (float*)alloc(16ull * 256 * 1024 * 4);
  float* PE1  = (float*)alloc(16ull * 256 * 4096 * 4);
  bf16* h1b[2]; float* c1b[2]; float* c2b[2]; bf16* h2b[2];
  for (int i = 0; i < 2; ++i) {
    h1b[i] = (bf16*)alloc(256ull * 1024 * 2);
    c1b[i] = (float*)alloc(256ull * 1024 * 4);
    c2b[i] = (float*)alloc(256ull * 1024 * 4);
    h2b[i] = (bf16*)alloc(256ull * 1024 * 2);
  }
  bf16* hist = (bf16*)alloc(256ull * 256 * 1024 * 2);
  size_t need_full = (size_t)(p - (char*)d_ws);
  bool primary = ws_size >= need_full;

  // ---- prep ----
  k_conv<<<8192, 256, 0, stream>>>(in_c, cbf, 2097152);
  k_conv<<<2048, 256, 0, stream>>>(in_Wout, wOUT, 524288);
  k_conv<<<8192, 256, 0, stream>>>(in_Winit, wINIT, 2097152);
  k_trans_wout<<<2048, 256, 0, stream>>>(in_Wout, wOUTT);
  k_reorder_g<<<16384, 256, 0, stream>>>(in_Whh1, wHH1);
  k_reorder_g<<<16384, 256, 0, stream>>>(in_Wih2, wIH2);
  k_reorder_g<<<16384, 256, 0, stream>>>(in_Whh2, wHH2);
  k_reorder_c<<<8192, 256, 0, stream>>>(in_Wih1, wIH1C, 0);
  k_reorder_c<<<8192, 256, 0, stream>>>(in_Wih1, wPREV, 512);
  k_bias<<<16, 256, 0, stream>>>(in_bih1, in_bhh1, in_bih2, in_bhh2, in_bout,
                                 in_Wih1, b1r, b2r, bfr);
  gemm_ep<0><<<dim3(16, 64), 256, 0, stream>>>(wPREV, wOUTT, 512, nullptr,
                                               nullptr, nullptr, wFOLD, nullptr, 0);
  gemm_ep<1><<<dim3(64, 64), 256, 0, stream>>>(cbf, wINIT, 512, in_binit,
                                               c1i, c2i, h1i, h2i, 0);
  gemm_ep<2><<<dim3(64, 64), 256, 0, stream>>>(cbf, wIH1C, 512, b1r,
                                               PE1, nullptr, nullptr, nullptr, 0);

  // ---- recurrence: 16 segments x 16 steps, 2 GEMM launches each ----
  const size_t S = 256ull * 1024;
  for (int s = 0; s < 16; ++s) {
    for (int t = 0; t < 16; ++t) {
      int gt = s * 16 + t;
      int cur = gt & 1, prv = cur ^ 1;
      const bf16* h2prev = (gt == 0) ? nullptr
                          : (primary ? hist + (size_t)(gt - 1) * S : h2b[prv]);
      // layer 1: g1 = PE1[s] + h1@W_hh1' + h2prev@W_fold'  (-b_fold at gt==0)
      rnn_step<<<256, 512, 0, stream>>>(
          (t == 0) ? h1i + (size_t)s * S : h1b[prv], h2prev,
          wHH1, wFOLD,
          PE1 + (size_t)s * 1048576, nullptr, (gt == 0) ? bfr : nullptr,
          (t == 0) ? c1i + (size_t)s * S : c1b[prv], c1b[cur], h1b[cur]);
      // layer 2: g2 = h1n@W_ih2' + h2@W_hh2' + b2
      rnn_step<<<256, 512, 0, stream>>>(
          h1b[cur],
          (t == 0) ? h2i + (size_t)s * S
                   : (primary ? hist + (size_t)(gt - 1) * S : h2b[prv]),
          wIH2, wHH2, nullptr, b2r, nullptr,
          (t == 0) ? c2i + (size_t)s * S : c2b[prv], c2b[cur],
          primary ? hist + (size_t)gt * S : h2b[cur]);
      if (!primary) {
        gemm_ep<3><<<dim3(8, 4), 256, 0, stream>>>(h2b[cur], wOUT, 1024, in_bout,
                                                   out, nullptr, nullptr, nullptr, gt);
      }
    }
  }

  // ---- outputs: one big GEMM over the h2 history ----
  if (primary) {
    gemm_ep<3><<<dim3(8, 1024), 256, 0, stream>>>(hist, wOUT, 1024, in_bout,
                                                  out, nullptr, nullptr, nullptr, 0);
  }
  k_ratio<<<1, 1, 0, stream>>>(out + (out_size - 1), in_epoch, in_k);
}